// Round 1
// baseline (1618.932 us; speedup 1.0000x reference)
//
#include <hip/hip_runtime.h>
#include <math.h>

#define NB 32
#define NH 32
#define DM 4096
#define DK 128
#define MAXC 1024
#define SINKN 4
#define WINDOWN 1020

// ---------------- RoPE table: cos/sin[m][j], m in [0,1024), j in [0,64) ---------
__global__ void k_rope_table(float* __restrict__ cosT, float* __restrict__ sinT) {
    int idx = blockIdx.x * 256 + threadIdx.x;   // 0..65535
    int m = idx >> 6, j = idx & 63;
    float e = (float)(2 * j) * (1.0f / 128.0f);
    float theta = powf(10000.0f, -e);
    float ang = (float)m * theta;
    float s, c;
    sincosf(ang, &s, &c);
    cosT[idx] = c;
    sinT[idx] = s;
}

// ---------------- Skinny GEMV: out[z][b][j] = sum_d x[b][d] * W_z[j][d] --------
// grid (128, 2, nmat), block 256. Split-K over 2 halves of d; writes partials.
__global__ __launch_bounds__(256)
void k_gemv_part(const float* __restrict__ x, const float* __restrict__ W0,
                 const float* __restrict__ W1, const float* __restrict__ W2,
                 float* __restrict__ part, int nmat) {
    const int t = threadIdx.x;
    const int b = t & 31;
    const int g = t >> 5;
    const int jt = blockIdx.x, y = blockIdx.y, z = blockIdx.z;
    const float* W = (z == 0) ? W0 : ((z == 1) ? W1 : W2);
    const int j = jt * 32 + g * 4;
    const float* xr = x + b * DM + y * 2048;
    const float* w0 = W + (size_t)j * DM + y * 2048;
    const float* w1 = w0 + DM;
    const float* w2 = w1 + DM;
    const float* w3 = w2 + DM;
    float a0 = 0.f, a1 = 0.f, a2 = 0.f, a3 = 0.f;
#pragma unroll 4
    for (int d = 0; d < 2048; d += 4) {
        float4 xv = *(const float4*)(xr + d);
        float4 wv;
        wv = *(const float4*)(w0 + d);
        a0 += xv.x * wv.x + xv.y * wv.y + xv.z * wv.z + xv.w * wv.w;
        wv = *(const float4*)(w1 + d);
        a1 += xv.x * wv.x + xv.y * wv.y + xv.z * wv.z + xv.w * wv.w;
        wv = *(const float4*)(w2 + d);
        a2 += xv.x * wv.x + xv.y * wv.y + xv.z * wv.z + xv.w * wv.w;
        wv = *(const float4*)(w3 + d);
        a3 += xv.x * wv.x + xv.y * wv.y + xv.z * wv.z + xv.w * wv.w;
    }
    float* o = part + (((size_t)y * nmat + z) * NB + b) * DM + j;
    o[0] = a0; o[1] = a1; o[2] = a2; o[3] = a3;
}

// ---------------- sum two split-K partials: o[i] = a[i] + a[i+n] ----------------
__global__ void k_reduce2(const float* __restrict__ a, float* __restrict__ o, int n) {
    int i = blockIdx.x * 256 + threadIdx.x;
    if (i < n) o[i] = a[i] + a[i + n];
}

// ---------------- attention -----------------------------------------------------
__device__ __forceinline__ int map_row(int i, int ins, int nTail, int wrap) {
    if (!wrap) return i;
    if (i < SINKN) return i;
    int k = i - SINKN;
    return (k < nTail) ? (ins + 1 + k) : (SINKN + (k - nTail));
}

__global__ __launch_bounds__(256)
void k_attn(const float* __restrict__ kc, const float* __restrict__ vc,
            const float* __restrict__ qkv, const float* __restrict__ cosT,
            const float* __restrict__ sinT, const int* __restrict__ seqp,
            float* __restrict__ aout) {
    const int b = blockIdx.y, h = blockIdx.x, t = threadIdx.x;
    const int seq = *seqp;
    int L, ins, wrap;
    if (seq < MAXC) { L = seq + 1; ins = seq; wrap = 0; }
    else { L = MAXC; ins = SINKN + (seq - SINKN) % WINDOWN; wrap = 1; }
    const int nTail = (MAXC - 1) - ins;

    __shared__ float qrot[DK];
    __shared__ float sc[MAXC];
    __shared__ float red[16];
    __shared__ float oacc[8][DK];

    const float* qp   = qkv + (size_t)b * DM + h * DK;
    const float* knew = qkv + (size_t)NB * DM + (size_t)b * DM + h * DK;
    const float* vnew = qkv + (size_t)2 * NB * DM + (size_t)b * DM + h * DK;
    const float* kbase = kc + ((size_t)(b * NH + h)) * MAXC * DK;
    const float* vbase = vc + ((size_t)(b * NH + h)) * MAXC * DK;

    // Q RoPE at position L-1, fold 1/sqrt(DK)
    if (t < DK) {
        int d = t, j = d & 63;
        float c = cosT[(L - 1) * 64 + j];
        float s = sinT[(L - 1) * 64 + j];
        float qv = qp[d], qo = qp[d ^ 64];
        float qr = (d < 64) ? (qv * c - qo * s) : (qv * c + qo * s);
        qrot[d] = qr * 0.08838834764831845f;  // 1/sqrt(128)
    }
    __syncthreads();

    // Phase 1: scores. half-wave (32 lanes) per K row; lane holds d4 = q32*4..+3
    {
        const int q32 = t & 31, hw = t >> 5;
        const int d4 = q32 * 4;
        const int jj = (q32 & 15) * 4;
        const float q0 = qrot[d4], q1 = qrot[d4 + 1], q2 = qrot[d4 + 2], q3 = qrot[d4 + 3];
        for (int i = hw; i < L; i += 8) {
            int row = map_row(i, ins, nTail, wrap);
            const float* kr = (i == L - 1) ? knew : (kbase + (size_t)row * DK);
            float4 k4 = *(const float4*)(kr + d4);
            float ox = __shfl_xor(k4.x, 16, 32);
            float oy = __shfl_xor(k4.y, 16, 32);
            float oz = __shfl_xor(k4.z, 16, 32);
            float ow = __shfl_xor(k4.w, 16, 32);
            float4 c4 = *(const float4*)(cosT + i * 64 + jj);
            float4 s4 = *(const float4*)(sinT + i * 64 + jj);
            float r0, r1, r2, r3;
            if (q32 < 16) {
                r0 = k4.x * c4.x - ox * s4.x;
                r1 = k4.y * c4.y - oy * s4.y;
                r2 = k4.z * c4.z - oz * s4.z;
                r3 = k4.w * c4.w - ow * s4.w;
            } else {
                r0 = k4.x * c4.x + ox * s4.x;
                r1 = k4.y * c4.y + oy * s4.y;
                r2 = k4.z * c4.z + oz * s4.z;
                r3 = k4.w * c4.w + ow * s4.w;
            }
            float part = q0 * r0 + q1 * r1 + q2 * r2 + q3 * r3;
            part += __shfl_xor(part, 1, 32);
            part += __shfl_xor(part, 2, 32);
            part += __shfl_xor(part, 4, 32);
            part += __shfl_xor(part, 8, 32);
            part += __shfl_xor(part, 16, 32);
            if (q32 == 0) sc[i] = part;
        }
    }
    __syncthreads();

    // Softmax over sc[0..L)
    float lm = -1e30f;
    for (int i = t; i < L; i += 256) lm = fmaxf(lm, sc[i]);
    for (int o = 32; o > 0; o >>= 1) lm = fmaxf(lm, __shfl_xor(lm, o, 64));
    if ((t & 63) == 0) red[t >> 6] = lm;
    __syncthreads();
    const float M = fmaxf(fmaxf(red[0], red[1]), fmaxf(red[2], red[3]));
    float ls = 0.f;
    for (int i = t; i < L; i += 256) {
        float p = __expf(sc[i] - M);
        sc[i] = p;
        ls += p;
    }
    for (int o = 32; o > 0; o >>= 1) ls += __shfl_xor(ls, o, 64);
    if ((t & 63) == 0) red[4 + (t >> 6)] = ls;
    __syncthreads();
    const float invS = 1.0f / (red[4] + red[5] + red[6] + red[7]);

    // Phase 2: out[d] = sum_i p_i * V[row(i)][d]; half-wave per V row, 8 stripes
    {
        const int q32 = t & 31, s8 = t >> 5;
        const int d4 = q32 * 4;
        float a0 = 0.f, a1 = 0.f, a2 = 0.f, a3 = 0.f;
        for (int i = s8; i < L; i += 8) {
            int row = map_row(i, ins, nTail, wrap);
            const float* vr = (i == L - 1) ? vnew : (vbase + (size_t)row * DK);
            float4 v4 = *(const float4*)(vr + d4);
            float p = sc[i];
            a0 += v4.x * p; a1 += v4.y * p; a2 += v4.z * p; a3 += v4.w * p;
        }
        *(float4*)(&oacc[s8][d4]) = make_float4(a0, a1, a2, a3);
    }
    __syncthreads();
    if (t < DK) {
        float o = 0.f;
#pragma unroll
        for (int s = 0; s < 8; s++) o += oacc[s][t];
        aout[(size_t)b * DM + h * DK + t] = o * invS;
    }
}

extern "C" void kernel_launch(void* const* d_in, const int* in_sizes, int n_in,
                              void* d_out, int out_size, void* d_ws, size_t ws_size,
                              hipStream_t stream) {
    const float* x_new = (const float*)d_in[0];
    const float* k_cache = (const float*)d_in[1];
    const float* v_cache = (const float*)d_in[2];
    const float* W_Q = (const float*)d_in[3];
    const float* W_K = (const float*)d_in[4];
    const float* W_V = (const float*)d_in[5];
    const float* W_O = (const float*)d_in[6];
    const int* seqp = (const int*)d_in[7];

    float* ws = (float*)d_ws;
    float* cosT = ws;                  // 65536
    float* sinT = cosT + 65536;        // 65536
    float* part = sinT + 65536;        // 2*3*32*4096 = 786432
    float* qkv  = part + 786432;       // 3*32*4096   = 393216
    float* aout = qkv + 393216;        // 32*4096     = 131072
    float* opart = aout + 131072;      // 2*32*4096   = 262144

    // 1. RoPE table
    k_rope_table<<<256, 256, 0, stream>>>(cosT, sinT);
    // 2. QKV projections (split-K=2 partials)
    k_gemv_part<<<dim3(128, 2, 3), 256, 0, stream>>>(x_new, W_Q, W_K, W_V, part, 3);
    // 3. reduce partials -> qkv[3][32][4096]
    k_reduce2<<<1536, 256, 0, stream>>>(part, qkv, 3 * NB * DM);
    // 4. attention -> aout[32][4096]
    k_attn<<<dim3(NH, NB), 256, 0, stream>>>(k_cache, v_cache, qkv, cosT, sinT, seqp, aout);
    // 5. O projection partials
    k_gemv_part<<<dim3(128, 2, 1), 256, 0, stream>>>(aout, W_O, W_O, W_O, opart, 1);
    // 6. reduce -> d_out
    k_reduce2<<<512, 256, 0, stream>>>(opart, (float*)d_out, NB * DM);
}